// Round 3
// baseline (2932.307 us; speedup 1.0000x reference)
//
#include <hip/hip_runtime.h>
#include <hip/hip_bf16.h>
#include <stdint.h>

// Problem constants
#define BT_N  32      // B*T
#define SEQL  512     // S
#define DM    768     // D_MODEL
#define NHEAD 12
#define HDIM  64
#define MTOT  (BT_N * SEQL)   // 16384 rows

typedef __bf16 bf16x8 __attribute__((ext_vector_type(8)));
typedef float  f32x4  __attribute__((ext_vector_type(4)));

__device__ __forceinline__ float b2f(uint16_t u)  { return __uint_as_float(((uint32_t)u) << 16); }
__device__ __forceinline__ uint16_t f2b(float f) {
    uint32_t u = __float_as_uint(f);
    return (uint16_t)((u + 0x7fffu + ((u >> 16) & 1u)) >> 16);  // RNE
}
__device__ __forceinline__ void split_bf16(float x, uint16_t& hi, uint16_t& lo) {
    hi = f2b(x);
    lo = f2b(x - b2f(hi));
}

// ---------------------------------------------------------------------------
// Fused QKV projection with split-bf16 (3-MFMA) fp32-accuracy GEMM.
// X (16384x768) fp32 row-major, W (768x768) fp32 row-major.
// out[z] = X @ W[z] + b[z]  (z=0 scaled by 1/8 for q/sqrt(hd)).
// Output fp32, layout (bt, h, s, d) for attention locality.
// Block: 256 thr = 4 waves, tile 64x64, BK=32, mfma_f32_16x16x32_bf16 x3.
// ---------------------------------------------------------------------------
__global__ __launch_bounds__(256) void qkv_gemm_kernel(
    const float* __restrict__ X,
    const float* __restrict__ Wq, const float* __restrict__ bq,
    const float* __restrict__ Wk, const float* __restrict__ bk,
    const float* __restrict__ Wv, const float* __restrict__ bv,
    float* __restrict__ qo, float* __restrict__ ko, float* __restrict__ vo)
{
    __shared__ uint16_t Ah[64][40], Al[64][40];   // A tile hi/lo [m][k], +8 pad
    __shared__ uint16_t Bh[64][40], Bl[64][40];   // B tile hi/lo transposed [n][k]

    const int m0 = blockIdx.x * 64;
    const int n0 = blockIdx.y * 64;
    const int z  = blockIdx.z;
    const float* W; const float* bias; float* outp;
    if (z == 0)      { W = Wq; bias = bq; outp = qo; }
    else if (z == 1) { W = Wk; bias = bk; outp = ko; }
    else             { W = Wv; bias = bv; outp = vo; }

    const int tid  = threadIdx.x;
    const int lane = tid & 63, wave = tid >> 6;
    const int quad = lane >> 4, l16 = lane & 15;
    const int wm = (wave & 1) * 32, wn = (wave >> 1) * 32;

    f32x4 acc00 = {0.f,0.f,0.f,0.f}, acc01 = {0.f,0.f,0.f,0.f};
    f32x4 acc10 = {0.f,0.f,0.f,0.f}, acc11 = {0.f,0.f,0.f,0.f};

    const int ar = tid >> 2,  ac = (tid & 3) * 8;   // A stage: 8 fp32/thread
    const int bkr = tid >> 3, bn = (tid & 7) * 8;   // B stage: 8 fp32/thread

    for (int k0 = 0; k0 < DM; k0 += 32) {
        __syncthreads();
        {   // stage A tile 64x32 (fp32 -> hi/lo bf16)
            const float* p = X + (size_t)(m0 + ar) * DM + k0 + ac;
            float4 f0 = *(const float4*)(p);
            float4 f1 = *(const float4*)(p + 4);
            float xx[8] = {f0.x,f0.y,f0.z,f0.w,f1.x,f1.y,f1.z,f1.w};
            #pragma unroll
            for (int j = 0; j < 8; j++) {
                uint16_t h, l; split_bf16(xx[j], h, l);
                Ah[ar][ac + j] = h; Al[ar][ac + j] = l;
            }
        }
        {   // stage B tile 32x64 transposed -> [n][k]
            const float* p = W + (size_t)(k0 + bkr) * DM + n0 + bn;
            float4 f0 = *(const float4*)(p);
            float4 f1 = *(const float4*)(p + 4);
            float xx[8] = {f0.x,f0.y,f0.z,f0.w,f1.x,f1.y,f1.z,f1.w};
            #pragma unroll
            for (int j = 0; j < 8; j++) {
                uint16_t h, l; split_bf16(xx[j], h, l);
                Bh[bn + j][bkr] = h; Bl[bn + j][bkr] = l;
            }
        }
        __syncthreads();
        // fragments: A[m=l16][k=quad*8+j], B[k=quad*8+j][n=l16] (from [n][k] LDS)
        bf16x8 ah0 = *(const bf16x8*)&Ah[wm + l16][quad * 8];
        bf16x8 ah1 = *(const bf16x8*)&Ah[wm + 16 + l16][quad * 8];
        bf16x8 al0 = *(const bf16x8*)&Al[wm + l16][quad * 8];
        bf16x8 al1 = *(const bf16x8*)&Al[wm + 16 + l16][quad * 8];
        bf16x8 bh0 = *(const bf16x8*)&Bh[wn + l16][quad * 8];
        bf16x8 bh1 = *(const bf16x8*)&Bh[wn + 16 + l16][quad * 8];
        bf16x8 bl0 = *(const bf16x8*)&Bl[wn + l16][quad * 8];
        bf16x8 bl1 = *(const bf16x8*)&Bl[wn + 16 + l16][quad * 8];
        // acc += Ahi*Bhi + Ahi*Blo + Alo*Bhi   (drop lo*lo)
        acc00 = __builtin_amdgcn_mfma_f32_16x16x32_bf16(al0, bh0, acc00, 0, 0, 0);
        acc00 = __builtin_amdgcn_mfma_f32_16x16x32_bf16(ah0, bl0, acc00, 0, 0, 0);
        acc00 = __builtin_amdgcn_mfma_f32_16x16x32_bf16(ah0, bh0, acc00, 0, 0, 0);
        acc01 = __builtin_amdgcn_mfma_f32_16x16x32_bf16(al0, bh1, acc01, 0, 0, 0);
        acc01 = __builtin_amdgcn_mfma_f32_16x16x32_bf16(ah0, bl1, acc01, 0, 0, 0);
        acc01 = __builtin_amdgcn_mfma_f32_16x16x32_bf16(ah0, bh1, acc01, 0, 0, 0);
        acc10 = __builtin_amdgcn_mfma_f32_16x16x32_bf16(al1, bh0, acc10, 0, 0, 0);
        acc10 = __builtin_amdgcn_mfma_f32_16x16x32_bf16(ah1, bl0, acc10, 0, 0, 0);
        acc10 = __builtin_amdgcn_mfma_f32_16x16x32_bf16(ah1, bh0, acc10, 0, 0, 0);
        acc11 = __builtin_amdgcn_mfma_f32_16x16x32_bf16(al1, bh1, acc11, 0, 0, 0);
        acc11 = __builtin_amdgcn_mfma_f32_16x16x32_bf16(ah1, bl1, acc11, 0, 0, 0);
        acc11 = __builtin_amdgcn_mfma_f32_16x16x32_bf16(ah1, bh1, acc11, 0, 0, 0);
    }

    const float scale = (z == 0) ? 0.125f : 1.0f;   // q / sqrt(64), after bias
    #pragma unroll
    for (int tm = 0; tm < 2; tm++) {
        #pragma unroll
        for (int tn = 0; tn < 2; tn++) {
            f32x4 a = (tm == 0) ? (tn == 0 ? acc00 : acc01)
                                : (tn == 0 ? acc10 : acc11);
            int n = n0 + wn + tn * 16 + l16;
            float bsv = bias[n];
            int hh = n >> 6, d = n & 63;
            #pragma unroll
            for (int r = 0; r < 4; r++) {
                int m = m0 + wm + tm * 16 + quad * 4 + r;   // C/D: row=quad*4+reg
                float val = (a[r] + bsv) * scale;
                int bt = m >> 9, s = m & 511;
                outp[(((size_t)bt * NHEAD + hh) * SEQL + s) * HDIM + d] = val;
            }
        }
    }
}

// ---------------------------------------------------------------------------
// Output projection: Y = ctx @ Wo + bo.  ctx (16384x768) bf16 row-major,
// Wo (768x768) fp32 row-major (bf16 at staging). Y FP32 direct to d_out.
// ---------------------------------------------------------------------------
__global__ __launch_bounds__(256) void out_proj_kernel(
    const uint16_t* __restrict__ A,  const float* __restrict__ W,
    const float* __restrict__ bias, float* __restrict__ Y)
{
    __shared__ uint16_t As[64][40];
    __shared__ uint16_t Bs[64][40];

    const int m0 = blockIdx.x * 64;
    const int n0 = blockIdx.y * 64;
    const int tid  = threadIdx.x;
    const int lane = tid & 63, wave = tid >> 6;
    const int quad = lane >> 4, l16 = lane & 15;
    const int wm = (wave & 1) * 32, wn = (wave >> 1) * 32;

    f32x4 acc00 = {0.f,0.f,0.f,0.f}, acc01 = {0.f,0.f,0.f,0.f};
    f32x4 acc10 = {0.f,0.f,0.f,0.f}, acc11 = {0.f,0.f,0.f,0.f};

    const int am = tid >> 2,  ak = (tid & 3) * 8;
    const int bkr = tid >> 3, bn = (tid & 7) * 8;

    for (int k0 = 0; k0 < DM; k0 += 32) {
        __syncthreads();
        uint4 av = *(const uint4*)(A + (size_t)(m0 + am) * DM + k0 + ak);
        *(uint4*)&As[am][ak] = av;
        {   // Wo fp32 -> bf16, transposed [n][k]
            const float* p = W + (size_t)(k0 + bkr) * DM + n0 + bn;
            float4 f0 = *(const float4*)(p);
            float4 f1 = *(const float4*)(p + 4);
            float xx[8] = {f0.x,f0.y,f0.z,f0.w,f1.x,f1.y,f1.z,f1.w};
            #pragma unroll
            for (int j = 0; j < 8; j++) Bs[bn + j][bkr] = f2b(xx[j]);
        }
        __syncthreads();
        bf16x8 a0 = *(const bf16x8*)&As[wm + l16][quad * 8];
        bf16x8 a1 = *(const bf16x8*)&As[wm + 16 + l16][quad * 8];
        bf16x8 b0 = *(const bf16x8*)&Bs[wn + l16][quad * 8];
        bf16x8 b1 = *(const bf16x8*)&Bs[wn + 16 + l16][quad * 8];
        acc00 = __builtin_amdgcn_mfma_f32_16x16x32_bf16(a0, b0, acc00, 0, 0, 0);
        acc01 = __builtin_amdgcn_mfma_f32_16x16x32_bf16(a0, b1, acc01, 0, 0, 0);
        acc10 = __builtin_amdgcn_mfma_f32_16x16x32_bf16(a1, b0, acc10, 0, 0, 0);
        acc11 = __builtin_amdgcn_mfma_f32_16x16x32_bf16(a1, b1, acc11, 0, 0, 0);
    }

    #pragma unroll
    for (int tm = 0; tm < 2; tm++) {
        #pragma unroll
        for (int tn = 0; tn < 2; tn++) {
            f32x4 a = (tm == 0) ? (tn == 0 ? acc00 : acc01)
                                : (tn == 0 ? acc10 : acc11);
            int n = n0 + wn + tn * 16 + l16;
            float bsv = bias[n];
            #pragma unroll
            for (int r = 0; r < 4; r++) {
                int m = m0 + wm + tm * 16 + quad * 4 + r;
                Y[(size_t)m * DM + n] = a[r] + bsv;   // FP32 output
            }
        }
    }
}

// ---------------------------------------------------------------------------
// Flash-style masked attention, all fp32. One block per (bt*H, 32-row Q tile).
// Online softmax over 64-key chunks, K/V staged fp32 in LDS.
// Mask: latent queries (q < n_latents) attend all; others same-modality only.
// ctx written as (bt*S+q, h*64+d) bf16 row-major (16384,768) for out-proj.
// ---------------------------------------------------------------------------
#define QT 32
#define KC 64

__global__ __launch_bounds__(256) void attn_kernel(
    const float* __restrict__ Q, const float* __restrict__ K,
    const float* __restrict__ V, const int* __restrict__ modality,
    const int* __restrict__ nlat_p, uint16_t* __restrict__ ctx)
{
    __shared__ float qs[QT][68];      // fp32 Q tile (stride 68: 16B-aligned rows)
    __shared__ float ks[KC][68];      // fp32 K chunk
    __shared__ float vs[KC][68];      // fp32 V chunk
    __shared__ float sc[QT][KC + 1];  // scores / probabilities
    __shared__ float os[QT][65];      // output accumulator
    __shared__ float mrow[QT], lrow[QT], arow[QT];
    __shared__ int   modq[QT], modk[KC];
    __shared__ char  qlat[QT];

    const int bh = blockIdx.x;
    const int bt = bh / NHEAD, h = bh % NHEAD;
    const int q0 = blockIdx.y * QT;
    const int tid = threadIdx.x;

    const size_t hb = ((size_t)(bt * NHEAD + h)) * SEQL * HDIM;
    const float* Qb = Q + hb;
    const float* Kb = K + hb;
    const float* Vb = V + hb;

    {   // load Q tile (already scaled+biased), init O
        int r = tid >> 3, c0 = (tid & 7) * 8;
        const float* p = Qb + (size_t)(q0 + r) * HDIM + c0;
        *(float4*)&qs[r][c0]     = *(const float4*)(p);
        *(float4*)&qs[r][c0 + 4] = *(const float4*)(p + 4);
        #pragma unroll
        for (int i = 0; i < 8; i++) os[r][c0 + i] = 0.f;
    }
    if (tid < QT) {
        mrow[tid] = -3e38f; lrow[tid] = 0.f;
        modq[tid] = modality[q0 + tid];
        qlat[tid] = ((q0 + tid) < nlat_p[0]) ? 1 : 0;
    }
    __syncthreads();

    for (int s0 = 0; s0 < SEQL; s0 += KC) {
        {   // stage K/V chunk: 64 rows x 64 cols fp32, 16 floats/thread each
            int r = tid >> 2, c0 = (tid & 3) * 16;
            const float* kp = Kb + (size_t)(s0 + r) * HDIM + c0;
            const float* vp = Vb + (size_t)(s0 + r) * HDIM + c0;
            #pragma unroll
            for (int i = 0; i < 4; i++) {
                *(float4*)&ks[r][c0 + 4*i] = *(const float4*)(kp + 4*i);
                *(float4*)&vs[r][c0 + 4*i] = *(const float4*)(vp + 4*i);
            }
        }
        if (tid < KC) modk[tid] = modality[s0 + tid];
        __syncthreads();

        {   // scores: thread t -> row r=t>>3, cols (t&7)+8i (strided)
            const int r = tid >> 3, cb = tid & 7;
            float acc[8] = {0.f,0.f,0.f,0.f,0.f,0.f,0.f,0.f};
            for (int d = 0; d < HDIM; d += 4) {
                float4 qv = *(const float4*)&qs[r][d];
                #pragma unroll
                for (int i = 0; i < 8; i++) {
                    int c = cb + 8 * i;
                    float4 kv = *(const float4*)&ks[c][d];
                    acc[i] += qv.x * kv.x + qv.y * kv.y + qv.z * kv.z + qv.w * kv.w;
                }
            }
            const bool lat = qlat[r]; const int mq = modq[r];
            #pragma unroll
            for (int i = 0; i < 8; i++) {
                int c = cb + 8 * i;
                bool valid = lat || (mq == modk[c]);
                sc[r][c] = valid ? acc[i] : -3e38f;
            }
        }
        __syncthreads();

        if (tid < QT) {   // chunk max, online-softmax rescale factor
            float mloc = -3e38f;
            for (int j = 0; j < KC; j++) mloc = fmaxf(mloc, sc[tid][j]);
            float mold = mrow[tid];
            float mnew = fmaxf(mold, mloc);
            arow[tid] = __expf(mold - mnew);   // ==1 when both -3e38 (all-masked chunk)
            mrow[tid] = mnew;
        }
        __syncthreads();

        {   // p = exp(s - m) with masked guard; rescale O
            int r = tid >> 3, c0 = (tid & 7) * 8;
            float mr = mrow[r], al = arow[r];
            #pragma unroll
            for (int i = 0; i < 8; i++) {
                float s = sc[r][c0 + i];
                sc[r][c0 + i] = (s <= -1e37f) ? 0.f : __expf(s - mr);
            }
            #pragma unroll
            for (int i = 0; i < 8; i++) os[r][c0 + i] *= al;
        }
        __syncthreads();

        if (tid < QT) {   // l update
            float sum = 0.f;
            for (int j = 0; j < KC; j++) sum += sc[tid][j];
            lrow[tid] = lrow[tid] * arow[tid] + sum;
        }
        {   // O += P @ V : thread t -> row r, dims d0..d0+7
            int r = tid >> 3, d0 = (tid & 7) * 8;
            float acc[8] = {0.f,0.f,0.f,0.f,0.f,0.f,0.f,0.f};
            for (int j = 0; j < KC; j++) {
                float p = sc[r][j];
                float4 v0 = *(const float4*)&vs[j][d0];
                float4 v1 = *(const float4*)&vs[j][d0 + 4];
                acc[0] += p * v0.x; acc[1] += p * v0.y;
                acc[2] += p * v0.z; acc[3] += p * v0.w;
                acc[4] += p * v1.x; acc[5] += p * v1.y;
                acc[6] += p * v1.z; acc[7] += p * v1.w;
            }
            #pragma unroll
            for (int i = 0; i < 8; i++) os[r][d0 + i] += acc[i];
        }
        __syncthreads();
    }

    {   // ctx = O / l  -> (bt*S + q)*768 + h*64 + d, bf16
        int r = tid >> 3, c0 = (tid & 7) * 8;
        float inv = 1.0f / lrow[r];
        uint16_t tmp[8];
        #pragma unroll
        for (int i = 0; i < 8; i++) tmp[i] = f2b(os[r][c0 + i] * inv);
        *(uint4*)(ctx + ((size_t)(bt * SEQL + q0 + r)) * DM + (size_t)h * HDIM + c0) =
            *(uint4*)tmp;
    }
}

// ---------------------------------------------------------------------------
extern "C" void kernel_launch(void* const* d_in, const int* in_sizes, int n_in,
                              void* d_out, int out_size, void* d_ws, size_t ws_size,
                              hipStream_t stream) {
    const float* X  = (const float*)d_in[0];
    const float* Wq = (const float*)d_in[1];
    const float* bq = (const float*)d_in[2];
    const float* Wk = (const float*)d_in[3];
    const float* bk = (const float*)d_in[4];
    const float* Wv = (const float*)d_in[5];
    const float* bv = (const float*)d_in[6];
    const float* Wo = (const float*)d_in[7];
    const float* bo = (const float*)d_in[8];
    const int* modality = (const int*)d_in[9];
    const int* nlat     = (const int*)d_in[10];

    const size_t per = (size_t)MTOT * DM;       // elements per buffer
    float* q_ws = (float*)d_ws;                 // (bt,h,s,d) fp32
    float* k_ws = q_ws + per;
    float* v_ws = k_ws + per;
    uint16_t* c_ws = (uint16_t*)(v_ws + per);   // ctx (bt*s, h*d) bf16 row-major

    qkv_gemm_kernel<<<dim3(MTOT / 64, DM / 64, 3), 256, 0, stream>>>(
        X, Wq, bq, Wk, bk, Wv, bv, q_ws, k_ws, v_ws);
    attn_kernel<<<dim3(BT_N * NHEAD, SEQL / QT), 256, 0, stream>>>(
        q_ws, k_ws, v_ws, modality, nlat, c_ws);
    out_proj_kernel<<<dim3(MTOT / 64, DM / 64), 256, 0, stream>>>(
        c_ws, Wo, bo, (float*)d_out);
}

// Round 4
// 867.055 us; speedup vs baseline: 3.3819x; 3.3819x over previous
//
#include <hip/hip_runtime.h>
#include <hip/hip_bf16.h>
#include <stdint.h>

// Problem constants
#define BT_N  32      // B*T
#define SEQL  512     // S
#define DM    768     // D_MODEL
#define NHEAD 12
#define HDIM  64
#define MTOT  (BT_N * SEQL)   // 16384 rows

typedef __bf16 bf16x8 __attribute__((ext_vector_type(8)));
typedef float  f32x4  __attribute__((ext_vector_type(4)));
typedef uint16_t u16x8 __attribute__((ext_vector_type(8)));

__device__ __forceinline__ float b2f(uint16_t u)  { return __uint_as_float(((uint32_t)u) << 16); }
__device__ __forceinline__ uint16_t f2b(float f) {
    uint32_t u = __float_as_uint(f);
    return (uint16_t)((u + 0x7fffu + ((u >> 16) & 1u)) >> 16);  // RNE
}
__device__ __forceinline__ void split_bf16(float x, uint16_t& hi, uint16_t& lo) {
    hi = f2b(x);
    lo = f2b(x - b2f(hi));
}
__device__ __forceinline__ uint32_t pack2(uint16_t a, uint16_t b) {
    return (uint32_t)a | ((uint32_t)b << 16);
}

// ---------------------------------------------------------------------------
// Fused QKV projection with split-bf16 (3-MFMA) fp32-accuracy GEMM.
// X (16384x768) fp32 row-major, W (768x768) fp32 row-major.
// out[z] = X @ W[z] + b[z]  (z=0 scaled by 1/8 for q/sqrt(hd)).
// Q,K out: (bt, h, s, d) fp32.  V out: (bt, h, d, s) fp32 (TRANSPOSED for
// conflict-free V staging in the attention kernel).
// ---------------------------------------------------------------------------
__global__ __launch_bounds__(256) void qkv_gemm_kernel(
    const float* __restrict__ X,
    const float* __restrict__ Wq, const float* __restrict__ bq,
    const float* __restrict__ Wk, const float* __restrict__ bk,
    const float* __restrict__ Wv, const float* __restrict__ bv,
    float* __restrict__ qo, float* __restrict__ ko, float* __restrict__ vo)
{
    __shared__ uint16_t Ah[64][40], Al[64][40];   // A tile hi/lo [m][k], +8 pad
    __shared__ uint16_t Bh[64][40], Bl[64][40];   // B tile hi/lo transposed [n][k]

    const int m0 = blockIdx.x * 64;
    const int n0 = blockIdx.y * 64;
    const int z  = blockIdx.z;
    const float* W; const float* bias; float* outp;
    if (z == 0)      { W = Wq; bias = bq; outp = qo; }
    else if (z == 1) { W = Wk; bias = bk; outp = ko; }
    else             { W = Wv; bias = bv; outp = vo; }

    const int tid  = threadIdx.x;
    const int lane = tid & 63, wave = tid >> 6;
    const int quad = lane >> 4, l16 = lane & 15;
    const int wm = (wave & 1) * 32, wn = (wave >> 1) * 32;

    f32x4 acc00 = {0.f,0.f,0.f,0.f}, acc01 = {0.f,0.f,0.f,0.f};
    f32x4 acc10 = {0.f,0.f,0.f,0.f}, acc11 = {0.f,0.f,0.f,0.f};

    const int ar = tid >> 2,  ac = (tid & 3) * 8;   // A stage: 8 fp32/thread
    const int bkr = tid >> 3, bn = (tid & 7) * 8;   // B stage: 8 fp32/thread

    for (int k0 = 0; k0 < DM; k0 += 32) {
        __syncthreads();
        {   // stage A tile 64x32 (fp32 -> hi/lo bf16)
            const float* p = X + (size_t)(m0 + ar) * DM + k0 + ac;
            float4 f0 = *(const float4*)(p);
            float4 f1 = *(const float4*)(p + 4);
            float xx[8] = {f0.x,f0.y,f0.z,f0.w,f1.x,f1.y,f1.z,f1.w};
            #pragma unroll
            for (int j = 0; j < 8; j++) {
                uint16_t h, l; split_bf16(xx[j], h, l);
                Ah[ar][ac + j] = h; Al[ar][ac + j] = l;
            }
        }
        {   // stage B tile 32x64 transposed -> [n][k]
            const float* p = W + (size_t)(k0 + bkr) * DM + n0 + bn;
            float4 f0 = *(const float4*)(p);
            float4 f1 = *(const float4*)(p + 4);
            float xx[8] = {f0.x,f0.y,f0.z,f0.w,f1.x,f1.y,f1.z,f1.w};
            #pragma unroll
            for (int j = 0; j < 8; j++) {
                uint16_t h, l; split_bf16(xx[j], h, l);
                Bh[bn + j][bkr] = h; Bl[bn + j][bkr] = l;
            }
        }
        __syncthreads();
        bf16x8 ah0 = *(const bf16x8*)&Ah[wm + l16][quad * 8];
        bf16x8 ah1 = *(const bf16x8*)&Ah[wm + 16 + l16][quad * 8];
        bf16x8 al0 = *(const bf16x8*)&Al[wm + l16][quad * 8];
        bf16x8 al1 = *(const bf16x8*)&Al[wm + 16 + l16][quad * 8];
        bf16x8 bh0 = *(const bf16x8*)&Bh[wn + l16][quad * 8];
        bf16x8 bh1 = *(const bf16x8*)&Bh[wn + 16 + l16][quad * 8];
        bf16x8 bl0 = *(const bf16x8*)&Bl[wn + l16][quad * 8];
        bf16x8 bl1 = *(const bf16x8*)&Bl[wn + 16 + l16][quad * 8];
        acc00 = __builtin_amdgcn_mfma_f32_16x16x32_bf16(al0, bh0, acc00, 0, 0, 0);
        acc00 = __builtin_amdgcn_mfma_f32_16x16x32_bf16(ah0, bl0, acc00, 0, 0, 0);
        acc00 = __builtin_amdgcn_mfma_f32_16x16x32_bf16(ah0, bh0, acc00, 0, 0, 0);
        acc01 = __builtin_amdgcn_mfma_f32_16x16x32_bf16(al0, bh1, acc01, 0, 0, 0);
        acc01 = __builtin_amdgcn_mfma_f32_16x16x32_bf16(ah0, bl1, acc01, 0, 0, 0);
        acc01 = __builtin_amdgcn_mfma_f32_16x16x32_bf16(ah0, bh1, acc01, 0, 0, 0);
        acc10 = __builtin_amdgcn_mfma_f32_16x16x32_bf16(al1, bh0, acc10, 0, 0, 0);
        acc10 = __builtin_amdgcn_mfma_f32_16x16x32_bf16(ah1, bl0, acc10, 0, 0, 0);
        acc10 = __builtin_amdgcn_mfma_f32_16x16x32_bf16(ah1, bh0, acc10, 0, 0, 0);
        acc11 = __builtin_amdgcn_mfma_f32_16x16x32_bf16(al1, bh1, acc11, 0, 0, 0);
        acc11 = __builtin_amdgcn_mfma_f32_16x16x32_bf16(ah1, bl1, acc11, 0, 0, 0);
        acc11 = __builtin_amdgcn_mfma_f32_16x16x32_bf16(ah1, bh1, acc11, 0, 0, 0);
    }

    const float scale = (z == 0) ? 0.125f : 1.0f;   // q / sqrt(64), after bias
    #pragma unroll
    for (int tm = 0; tm < 2; tm++) {
        #pragma unroll
        for (int tn = 0; tn < 2; tn++) {
            f32x4 a = (tm == 0) ? (tn == 0 ? acc00 : acc01)
                                : (tn == 0 ? acc10 : acc11);
            int n = n0 + wn + tn * 16 + l16;
            float bsv = bias[n];
            int hh = n >> 6, d = n & 63;
            #pragma unroll
            for (int r = 0; r < 4; r++) {
                int m = m0 + wm + tm * 16 + quad * 4 + r;   // C/D: row=quad*4+reg
                float val = (a[r] + bsv) * scale;
                int bt = m >> 9, s = m & 511;
                size_t idx;
                if (z == 2)  // V transposed: (bt, h, d, s)
                    idx = (((size_t)bt * NHEAD + hh) * HDIM + d) * SEQL + s;
                else         // Q,K: (bt, h, s, d)
                    idx = (((size_t)bt * NHEAD + hh) * SEQL + s) * HDIM + d;
                outp[idx] = val;
            }
        }
    }
}

// ---------------------------------------------------------------------------
// Output projection: Y = ctx @ Wo + bo.  ctx (16384x768) bf16 row-major,
// Wo (768x768) fp32 row-major (bf16 at staging). Y FP32 direct to d_out.
// ---------------------------------------------------------------------------
__global__ __launch_bounds__(256) void out_proj_kernel(
    const uint16_t* __restrict__ A,  const float* __restrict__ W,
    const float* __restrict__ bias, float* __restrict__ Y)
{
    __shared__ uint16_t As[64][40];
    __shared__ uint16_t Bs[64][40];

    const int m0 = blockIdx.x * 64;
    const int n0 = blockIdx.y * 64;
    const int tid  = threadIdx.x;
    const int lane = tid & 63, wave = tid >> 6;
    const int quad = lane >> 4, l16 = lane & 15;
    const int wm = (wave & 1) * 32, wn = (wave >> 1) * 32;

    f32x4 acc00 = {0.f,0.f,0.f,0.f}, acc01 = {0.f,0.f,0.f,0.f};
    f32x4 acc10 = {0.f,0.f,0.f,0.f}, acc11 = {0.f,0.f,0.f,0.f};

    const int am = tid >> 2,  ak = (tid & 3) * 8;
    const int bkr = tid >> 3, bn = (tid & 7) * 8;

    for (int k0 = 0; k0 < DM; k0 += 32) {
        __syncthreads();
        uint4 av = *(const uint4*)(A + (size_t)(m0 + am) * DM + k0 + ak);
        *(uint4*)&As[am][ak] = av;
        {   // Wo fp32 -> bf16, transposed [n][k]
            const float* p = W + (size_t)(k0 + bkr) * DM + n0 + bn;
            float4 f0 = *(const float4*)(p);
            float4 f1 = *(const float4*)(p + 4);
            float xx[8] = {f0.x,f0.y,f0.z,f0.w,f1.x,f1.y,f1.z,f1.w};
            #pragma unroll
            for (int j = 0; j < 8; j++) Bs[bn + j][bkr] = f2b(xx[j]);
        }
        __syncthreads();
        bf16x8 a0 = *(const bf16x8*)&As[wm + l16][quad * 8];
        bf16x8 a1 = *(const bf16x8*)&As[wm + 16 + l16][quad * 8];
        bf16x8 b0 = *(const bf16x8*)&Bs[wn + l16][quad * 8];
        bf16x8 b1 = *(const bf16x8*)&Bs[wn + 16 + l16][quad * 8];
        acc00 = __builtin_amdgcn_mfma_f32_16x16x32_bf16(a0, b0, acc00, 0, 0, 0);
        acc01 = __builtin_amdgcn_mfma_f32_16x16x32_bf16(a0, b1, acc01, 0, 0, 0);
        acc10 = __builtin_amdgcn_mfma_f32_16x16x32_bf16(a1, b0, acc10, 0, 0, 0);
        acc11 = __builtin_amdgcn_mfma_f32_16x16x32_bf16(a1, b1, acc11, 0, 0, 0);
    }

    #pragma unroll
    for (int tm = 0; tm < 2; tm++) {
        #pragma unroll
        for (int tn = 0; tn < 2; tn++) {
            f32x4 a = (tm == 0) ? (tn == 0 ? acc00 : acc01)
                                : (tn == 0 ? acc10 : acc11);
            int n = n0 + wn + tn * 16 + l16;
            float bsv = bias[n];
            #pragma unroll
            for (int r = 0; r < 4; r++) {
                int m = m0 + wm + tm * 16 + quad * 4 + r;
                Y[(size_t)m * DM + n] = a[r] + bsv;   // FP32 output
            }
        }
    }
}

// ---------------------------------------------------------------------------
// MFMA flash attention. One block = (bt*h, 128 Q-rows); 4 waves x 32 rows.
// QK^T via split-bf16 (3 MFMA, fp32-grade scores); softmax in registers
// (C-layout row stats via __shfl_xor over l16); P->A-layout via wave-private
// LDS round-trip; PV in plain bf16 MFMA.
// Q,K in (bt,h,s,d) fp32; V in (bt,h,d,s) fp32; ctx out (bt*S+q, h*64+d) bf16.
// ---------------------------------------------------------------------------
#define QTILE 128

__global__ __launch_bounds__(256) void attn_mfma_kernel(
    const float* __restrict__ Q, const float* __restrict__ K,
    const float* __restrict__ Vt, const int* __restrict__ modality,
    const int* __restrict__ nlat_p, uint16_t* __restrict__ ctx)
{
    __shared__ uint16_t Kh[64][72];   // K chunk hi  [key][d], stride 72 (144B)
    __shared__ uint16_t Kl[64][72];   // K chunk lo
    __shared__ uint16_t Vs[64][72];   // V chunk     [d][key]
    __shared__ uint16_t Ps[QTILE][72];// P           [qrow][key], wave-private rows
    __shared__ int modk_s[64];

    const int bh = blockIdx.x;
    const int bt = bh / NHEAD, h = bh % NHEAD;
    const int q0 = blockIdx.y * QTILE;
    const int tid = threadIdx.x, lane = tid & 63, wave = tid >> 6;
    const int quad = lane >> 4, l16 = lane & 15;
    const int wq = wave * 32;

    const float* Qb = Q  + (size_t)bh * SEQL * HDIM;
    const float* Kb = K  + (size_t)bh * SEQL * HDIM;
    const float* Vb = Vt + (size_t)bh * HDIM * SEQL;
    const int nlat = nlat_p[0];

    // --- Q fragments (hi/lo split), held in registers for the whole kernel
    bf16x8 qh[2][2], ql[2][2];
    #pragma unroll
    for (int t = 0; t < 2; t++) {
        #pragma unroll
        for (int ks = 0; ks < 2; ks++) {
            const float* p = Qb + (size_t)(q0 + wq + t*16 + l16) * HDIM + ks*32 + quad*8;
            float4 f0 = *(const float4*)p;
            float4 f1 = *(const float4*)(p + 4);
            float xx[8] = {f0.x,f0.y,f0.z,f0.w,f1.x,f1.y,f1.z,f1.w};
            u16x8 hu, lu;
            #pragma unroll
            for (int j = 0; j < 8; j++) {
                uint16_t hh_, ll_; split_bf16(xx[j], hh_, ll_);
                hu[j] = hh_; lu[j] = ll_;
            }
            qh[t][ks] = __builtin_bit_cast(bf16x8, hu);
            ql[t][ks] = __builtin_bit_cast(bf16x8, lu);
        }
    }

    // per-row mask data (rows quad*4+r of each m-tile)
    int  mq[2][4]; bool lat_[2][4];
    #pragma unroll
    for (int t = 0; t < 2; t++)
        #pragma unroll
        for (int r = 0; r < 4; r++) {
            int row = q0 + wq + t*16 + quad*4 + r;
            mq[t][r]   = modality[row];
            lat_[t][r] = row < nlat;
        }

    float mrow[2][4], lrow[2][4];
    #pragma unroll
    for (int t = 0; t < 2; t++)
        #pragma unroll
        for (int r = 0; r < 4; r++) { mrow[t][r] = -3e38f; lrow[t][r] = 0.f; }
    f32x4 O[2][4];
    #pragma unroll
    for (int t = 0; t < 2; t++)
        #pragma unroll
        for (int dt = 0; dt < 4; dt++) O[t][dt] = (f32x4){0.f,0.f,0.f,0.f};

    for (int s0 = 0; s0 < SEQL; s0 += 64) {
        __syncthreads();
        {   // stage K chunk hi/lo: thread -> key=tid>>2, 16 d's
            int key = tid >> 2, d0 = (tid & 3) * 16;
            const float* kp = Kb + (size_t)(s0 + key) * HDIM + d0;
            float4 f0 = *(const float4*)(kp);
            float4 f1 = *(const float4*)(kp + 4);
            float4 f2 = *(const float4*)(kp + 8);
            float4 f3 = *(const float4*)(kp + 12);
            float xx[16] = {f0.x,f0.y,f0.z,f0.w,f1.x,f1.y,f1.z,f1.w,
                            f2.x,f2.y,f2.z,f2.w,f3.x,f3.y,f3.z,f3.w};
            uint16_t hh[16], ll[16];
            #pragma unroll
            for (int j = 0; j < 16; j++) split_bf16(xx[j], hh[j], ll[j]);
            #pragma unroll
            for (int g = 0; g < 2; g++) {
                uint4 uh = {pack2(hh[8*g+0],hh[8*g+1]), pack2(hh[8*g+2],hh[8*g+3]),
                            pack2(hh[8*g+4],hh[8*g+5]), pack2(hh[8*g+6],hh[8*g+7])};
                uint4 ul = {pack2(ll[8*g+0],ll[8*g+1]), pack2(ll[8*g+2],ll[8*g+3]),
                            pack2(ll[8*g+4],ll[8*g+5]), pack2(ll[8*g+6],ll[8*g+7])};
                *(uint4*)&Kh[key][d0 + 8*g] = uh;
                *(uint4*)&Kl[key][d0 + 8*g] = ul;
            }
        }
        {   // stage V chunk (global already transposed): thread -> d=tid>>2, 16 keys
            int d = tid >> 2, c0 = (tid & 3) * 16;
            const float* vp = Vb + (size_t)d * SEQL + s0 + c0;
            float4 f0 = *(const float4*)(vp);
            float4 f1 = *(const float4*)(vp + 4);
            float4 f2 = *(const float4*)(vp + 8);
            float4 f3 = *(const float4*)(vp + 12);
            float xx[16] = {f0.x,f0.y,f0.z,f0.w,f1.x,f1.y,f1.z,f1.w,
                            f2.x,f2.y,f2.z,f2.w,f3.x,f3.y,f3.z,f3.w};
            uint16_t vv[16];
            #pragma unroll
            for (int j = 0; j < 16; j++) vv[j] = f2b(xx[j]);
            #pragma unroll
            for (int g = 0; g < 2; g++) {
                uint4 u = {pack2(vv[8*g+0],vv[8*g+1]), pack2(vv[8*g+2],vv[8*g+3]),
                           pack2(vv[8*g+4],vv[8*g+5]), pack2(vv[8*g+6],vv[8*g+7])};
                *(uint4*)&Vs[d][c0 + 8*g] = u;
            }
        }
        if (tid < 64) modk_s[tid] = modality[s0 + tid];
        __syncthreads();

        // --- scores: S[t][n] (16q x 16k tiles), split-bf16 3-MFMA
        f32x4 S[2][4];
        #pragma unroll
        for (int t = 0; t < 2; t++)
            #pragma unroll
            for (int n = 0; n < 4; n++) S[t][n] = (f32x4){0.f,0.f,0.f,0.f};
        #pragma unroll
        for (int n = 0; n < 4; n++) {
            #pragma unroll
            for (int ks = 0; ks < 2; ks++) {
                bf16x8 kh = *(const bf16x8*)&Kh[n*16 + l16][ks*32 + quad*8];
                bf16x8 kl = *(const bf16x8*)&Kl[n*16 + l16][ks*32 + quad*8];
                #pragma unroll
                for (int t = 0; t < 2; t++) {
                    S[t][n] = __builtin_amdgcn_mfma_f32_16x16x32_bf16(ql[t][ks], kh, S[t][n], 0, 0, 0);
                    S[t][n] = __builtin_amdgcn_mfma_f32_16x16x32_bf16(qh[t][ks], kl, S[t][n], 0, 0, 0);
                    S[t][n] = __builtin_amdgcn_mfma_f32_16x16x32_bf16(qh[t][ks], kh, S[t][n], 0, 0, 0);
                }
            }
        }

        // --- mask (C layout: col = n*16+l16, row = quad*4+r)
        int mk[4];
        #pragma unroll
        for (int n = 0; n < 4; n++) mk[n] = modk_s[n*16 + l16];
        #pragma unroll
        for (int t = 0; t < 2; t++)
            #pragma unroll
            for (int n = 0; n < 4; n++)
                #pragma unroll
                for (int r = 0; r < 4; r++)
                    if (!(lat_[t][r] || (mq[t][r] == mk[n]))) S[t][n][r] = -3e38f;

        // --- online softmax per row (shuffle over l16 within quad)
        #pragma unroll
        for (int t = 0; t < 2; t++) {
            #pragma unroll
            for (int r = 0; r < 4; r++) {
                float mc = fmaxf(fmaxf(S[t][0][r], S[t][1][r]),
                                 fmaxf(S[t][2][r], S[t][3][r]));
                #pragma unroll
                for (int off = 1; off <= 8; off <<= 1)
                    mc = fmaxf(mc, __shfl_xor(mc, off, 64));
                float mo = mrow[t][r];
                float mn = fmaxf(mo, mc);
                float al = __expf(mo - mn);
                float g  = (mn <= -1e37f) ? 0.f : 1.f;   // all-masked-so-far guard
                float sum = 0.f;
                #pragma unroll
                for (int n = 0; n < 4; n++) {
                    float p = __expf(S[t][n][r] - mn) * g;
                    Ps[wq + t*16 + quad*4 + r][n*16 + l16] = f2b(p);
                    sum += p;
                }
                #pragma unroll
                for (int off = 1; off <= 8; off <<= 1)
                    sum += __shfl_xor(sum, off, 64);
                lrow[t][r] = lrow[t][r] * al + sum;
                mrow[t][r] = mn;
                #pragma unroll
                for (int dt = 0; dt < 4; dt++) O[t][dt][r] *= al;
            }
        }

        // --- PV: O += P @ V   (P from wave-private LDS rows; bf16 MFMA)
        #pragma unroll
        for (int ks = 0; ks < 2; ks++) {
            bf16x8 pa[2];
            #pragma unroll
            for (int t = 0; t < 2; t++)
                pa[t] = *(const bf16x8*)&Ps[wq + t*16 + l16][ks*32 + quad*8];
            #pragma unroll
            for (int dt = 0; dt < 4; dt++) {
                bf16x8 vb = *(const bf16x8*)&Vs[dt*16 + l16][ks*32 + quad*8];
                #pragma unroll
                for (int t = 0; t < 2; t++)
                    O[t][dt] = __builtin_amdgcn_mfma_f32_16x16x32_bf16(pa[t], vb, O[t][dt], 0, 0, 0);
            }
        }
    }

    // --- epilogue: ctx = O / l, bf16, (bt*S+q)*768 + h*64 + d
    #pragma unroll
    for (int t = 0; t < 2; t++) {
        float inv[4];
        #pragma unroll
        for (int r = 0; r < 4; r++) inv[r] = 1.0f / fmaxf(lrow[t][r], 1e-30f);
        #pragma unroll
        for (int dt = 0; dt < 4; dt++) {
            #pragma unroll
            for (int r = 0; r < 4; r++) {
                int row = q0 + wq + t*16 + quad*4 + r;
                ctx[(size_t)(bt * SEQL + row) * DM + h*HDIM + dt*16 + l16] =
                    f2b(O[t][dt][r] * inv[r]);
            }
        }
    }
}

// ---------------------------------------------------------------------------
extern "C" void kernel_launch(void* const* d_in, const int* in_sizes, int n_in,
                              void* d_out, int out_size, void* d_ws, size_t ws_size,
                              hipStream_t stream) {
    const float* X  = (const float*)d_in[0];
    const float* Wq = (const float*)d_in[1];
    const float* bq = (const float*)d_in[2];
    const float* Wk = (const float*)d_in[3];
    const float* bk = (const float*)d_in[4];
    const float* Wv = (const float*)d_in[5];
    const float* bv = (const float*)d_in[6];
    const float* Wo = (const float*)d_in[7];
    const float* bo = (const float*)d_in[8];
    const int* modality = (const int*)d_in[9];
    const int* nlat     = (const int*)d_in[10];

    const size_t per = (size_t)MTOT * DM;       // elements per buffer
    float* q_ws = (float*)d_ws;                 // (bt,h,s,d) fp32
    float* k_ws = q_ws + per;                   // (bt,h,s,d) fp32
    float* v_ws = k_ws + per;                   // (bt,h,d,s) fp32 (transposed)
    uint16_t* c_ws = (uint16_t*)(v_ws + per);   // ctx (bt*s, h*d) bf16 row-major

    qkv_gemm_kernel<<<dim3(MTOT / 64, DM / 64, 3), 256, 0, stream>>>(
        X, Wq, bq, Wk, bk, Wv, bv, q_ws, k_ws, v_ws);
    attn_mfma_kernel<<<dim3(BT_N * NHEAD, SEQL / QTILE), 256, 0, stream>>>(
        q_ws, k_ws, v_ws, modality, nlat, c_ws);
    out_proj_kernel<<<dim3(MTOT / 64, DM / 64), 256, 0, stream>>>(
        c_ws, Wo, bo, (float*)d_out);
}

// Round 5
// 523.788 us; speedup vs baseline: 5.5983x; 1.6554x over previous
//
#include <hip/hip_runtime.h>
#include <hip/hip_bf16.h>
#include <stdint.h>

// Problem constants
#define BT_N  32      // B*T
#define SEQL  512     // S
#define DM    768     // D_MODEL
#define NHEAD 12
#define HDIM  64
#define MTOT  (BT_N * SEQL)   // 16384 rows

typedef __bf16 bf16x8 __attribute__((ext_vector_type(8)));
typedef float  f32x4  __attribute__((ext_vector_type(4)));

__device__ __forceinline__ float b2f(uint16_t u)  { return __uint_as_float(((uint32_t)u) << 16); }
__device__ __forceinline__ uint16_t f2b(float f) {
    uint32_t u = __float_as_uint(f);
    return (uint16_t)((u + 0x7fffu + ((u >> 16) & 1u)) >> 16);  // RNE
}
__device__ __forceinline__ void split_bf16(float x, uint16_t& hi, uint16_t& lo) {
    hi = f2b(x);
    lo = f2b(x - b2f(hi));
}

// ---------------------------------------------------------------------------
// Prepass 1: X fp32 -> Xh, Xl bf16 (hi/lo split). 4 elems/thread.
// ---------------------------------------------------------------------------
__global__ __launch_bounds__(256) void split_x_kernel(
    const float* __restrict__ X, uint16_t* __restrict__ Xh, uint16_t* __restrict__ Xl)
{
    size_t i = ((size_t)blockIdx.x * 256 + threadIdx.x) * 4;
    float4 v = *(const float4*)(X + i);
    float xx[4] = {v.x, v.y, v.z, v.w};
    ushort4 h, l;
    uint16_t hh, ll;
    split_bf16(xx[0], hh, ll); h.x = hh; l.x = ll;
    split_bf16(xx[1], hh, ll); h.y = hh; l.y = ll;
    split_bf16(xx[2], hh, ll); h.z = hh; l.z = ll;
    split_bf16(xx[3], hh, ll); h.w = hh; l.w = ll;
    *(ushort4*)(Xh + i) = h;
    *(ushort4*)(Xl + i) = l;
}

// ---------------------------------------------------------------------------
// Prepass 2: weight transpose (+split for Wq,Wk). W row-major (k,n) fp32 ->
// WT [n][k] bf16 (hi, and lo for z<2). 32x32 LDS tile transpose.
// z: 0=Wq(split), 1=Wk(split), 2=Wv(plain), 3=Wo(plain)
// ---------------------------------------------------------------------------
__global__ __launch_bounds__(256) void wprep_kernel(
    const float* __restrict__ Wq, const float* __restrict__ Wk,
    const float* __restrict__ Wv, const float* __restrict__ Wo,
    uint16_t* __restrict__ WqTh, uint16_t* __restrict__ WqTl,
    uint16_t* __restrict__ WkTh, uint16_t* __restrict__ WkTl,
    uint16_t* __restrict__ WvT,  uint16_t* __restrict__ WoT)
{
    __shared__ float tile[32][33];
    const int z = blockIdx.z;
    const float* W; uint16_t* Th; uint16_t* Tl;
    if (z == 0)      { W = Wq; Th = WqTh; Tl = WqTl; }
    else if (z == 1) { W = Wk; Th = WkTh; Tl = WkTl; }
    else if (z == 2) { W = Wv; Th = WvT;  Tl = nullptr; }
    else             { W = Wo; Th = WoT;  Tl = nullptr; }

    const int k0 = blockIdx.x * 32, n0 = blockIdx.y * 32;
    const int tid = threadIdx.x;
    {
        int r = tid >> 3, c = (tid & 7) * 4;
        *(float4*)&tile[r][c] = *(const float4*)(W + (size_t)(k0 + r) * DM + n0 + c);
    }
    __syncthreads();
    {
        int nl = tid >> 3, kk = (tid & 7) * 4;
        ushort4 h, l;
        uint16_t hh, ll;
        float v0 = tile[kk + 0][nl], v1 = tile[kk + 1][nl];
        float v2 = tile[kk + 2][nl], v3 = tile[kk + 3][nl];
        split_bf16(v0, hh, ll); h.x = hh; l.x = ll;
        split_bf16(v1, hh, ll); h.y = hh; l.y = ll;
        split_bf16(v2, hh, ll); h.z = hh; l.z = ll;
        split_bf16(v3, hh, ll); h.w = hh; l.w = ll;
        size_t o = (size_t)(n0 + nl) * DM + k0 + kk;
        *(ushort4*)(Th + o) = h;
        if (Tl) *(ushort4*)(Tl + o) = l;
    }
}

// ---------------------------------------------------------------------------
// QKV GEMM v2: pure bf16 MFMA, pre-split/pre-transposed operands.
// Block: 256 thr, tile 128(m) x 64(n), BK=64. Wave: 2 m-tiles x 4 n-tiles.
// z=0 (Q): 3 passes (XhWh, XlWh, XhWl), scale 1/8, out hi/lo (bt,h,s,d)
// z=1 (K): same, scale 1, out hi/lo
// z=2 (V): 1 pass (XhWv), out bf16 transposed (bt,h,d,s)
// ---------------------------------------------------------------------------
__global__ __launch_bounds__(256) void qkv_gemm_v2(
    const uint16_t* __restrict__ Xh, const uint16_t* __restrict__ Xl,
    const uint16_t* __restrict__ WqTh, const uint16_t* __restrict__ WqTl,
    const uint16_t* __restrict__ WkTh, const uint16_t* __restrict__ WkTl,
    const uint16_t* __restrict__ WvT,
    const float* __restrict__ bq, const float* __restrict__ bk, const float* __restrict__ bv,
    uint16_t* __restrict__ Qh, uint16_t* __restrict__ Ql,
    uint16_t* __restrict__ Kh, uint16_t* __restrict__ Kl,
    uint16_t* __restrict__ Vt)
{
    __shared__ uint16_t As[128][72];   // [m][k], stride 144 B (9x16B: odd multiple)
    __shared__ uint16_t Bs[64][72];    // [n][k]

    const int m0 = blockIdx.x * 128;
    const int n0 = blockIdx.y * 64;
    const int z  = blockIdx.z;

    const uint16_t* Ap[3]; const uint16_t* Bp[3]; int npass;
    const float* bias;
    if (z == 0) { Ap[0]=Xh; Ap[1]=Xl; Ap[2]=Xh; Bp[0]=WqTh; Bp[1]=WqTh; Bp[2]=WqTl; npass=3; bias=bq; }
    else if (z == 1) { Ap[0]=Xh; Ap[1]=Xl; Ap[2]=Xh; Bp[0]=WkTh; Bp[1]=WkTh; Bp[2]=WkTl; npass=3; bias=bk; }
    else { Ap[0]=Xh; Bp[0]=WvT; npass=1; bias=bv; }

    const int tid  = threadIdx.x;
    const int lane = tid & 63, wave = tid >> 6;
    const int quad = lane >> 4, l16 = lane & 15;
    const int wq = wave * 32;

    f32x4 acc[2][4];
    #pragma unroll
    for (int t = 0; t < 2; t++)
        #pragma unroll
        for (int nt = 0; nt < 4; nt++) acc[t][nt] = (f32x4){0.f,0.f,0.f,0.f};

    const int sr = tid >> 3, sc = (tid & 7) * 8;   // staging: 16B contiguous per thread

    for (int p = 0; p < npass; p++) {
        const uint16_t* A = Ap[p];
        const uint16_t* B = Bp[p];
        for (int k0 = 0; k0 < DM; k0 += 64) {
            __syncthreads();
            #pragma unroll
            for (int i = 0; i < 4; i++) {   // A tile 128x64
                int r = i * 32 + sr;
                *(uint4*)&As[r][sc] = *(const uint4*)(A + (size_t)(m0 + r) * DM + k0 + sc);
            }
            #pragma unroll
            for (int i = 0; i < 2; i++) {   // B tile 64x64
                int r = i * 32 + sr;
                *(uint4*)&Bs[r][sc] = *(const uint4*)(B + (size_t)(n0 + r) * DM + k0 + sc);
            }
            __syncthreads();
            #pragma unroll
            for (int ksub = 0; ksub < 2; ksub++) {
                bf16x8 a0 = *(const bf16x8*)&As[wq + l16][ksub * 32 + quad * 8];
                bf16x8 a1 = *(const bf16x8*)&As[wq + 16 + l16][ksub * 32 + quad * 8];
                bf16x8 bf[4];
                #pragma unroll
                for (int nt = 0; nt < 4; nt++)
                    bf[nt] = *(const bf16x8*)&Bs[nt * 16 + l16][ksub * 32 + quad * 8];
                #pragma unroll
                for (int nt = 0; nt < 4; nt++) {
                    acc[0][nt] = __builtin_amdgcn_mfma_f32_16x16x32_bf16(a0, bf[nt], acc[0][nt], 0, 0, 0);
                    acc[1][nt] = __builtin_amdgcn_mfma_f32_16x16x32_bf16(a1, bf[nt], acc[1][nt], 0, 0, 0);
                }
            }
        }
    }

    // epilogue
    const float scale = (z == 0) ? 0.125f : 1.0f;
    uint16_t* OutH = (z == 0) ? Qh : Kh;
    uint16_t* OutL = (z == 0) ? Ql : Kl;
    #pragma unroll
    for (int t = 0; t < 2; t++) {
        #pragma unroll
        for (int nt = 0; nt < 4; nt++) {
            int n = n0 + nt * 16 + l16;
            float bsv = bias[n];
            int hh = n >> 6, d = n & 63;
            int mbase = m0 + wq + t * 16 + quad * 4;   // C/D: row = quad*4 + r
            if (z == 2) {
                // V transposed (bt,h,d,s): r -> consecutive s, pack ushort4
                int bt = mbase >> 9, sb = mbase & 511;
                ushort4 pk;
                pk.x = f2b(acc[t][nt][0] + bsv);
                pk.y = f2b(acc[t][nt][1] + bsv);
                pk.z = f2b(acc[t][nt][2] + bsv);
                pk.w = f2b(acc[t][nt][3] + bsv);
                *(ushort4*)&Vt[(((size_t)bt * NHEAD + hh) * HDIM + d) * SEQL + sb] = pk;
            } else {
                #pragma unroll
                for (int r = 0; r < 4; r++) {
                    int m = mbase + r;
                    float val = (acc[t][nt][r] + bsv) * scale;
                    uint16_t vh, vl; split_bf16(val, vh, vl);
                    int bt = m >> 9, s = m & 511;
                    size_t idx = (((size_t)bt * NHEAD + hh) * SEQL + s) * HDIM + d;
                    OutH[idx] = vh; OutL[idx] = vl;
                }
            }
        }
    }
}

// ---------------------------------------------------------------------------
// Output projection v2: Y = ctx @ Wo + bo. ctx bf16 row-major, WoT [n][k] bf16.
// Same 128x64 structure, 1 pass. Y fp32 to d_out.
// ---------------------------------------------------------------------------
__global__ __launch_bounds__(256) void out_proj_v2(
    const uint16_t* __restrict__ A, const uint16_t* __restrict__ WoT,
    const float* __restrict__ bias, float* __restrict__ Y)
{
    __shared__ uint16_t As[128][72];
    __shared__ uint16_t Bs[64][72];

    const int m0 = blockIdx.x * 128;
    const int n0 = blockIdx.y * 64;
    const int tid  = threadIdx.x;
    const int lane = tid & 63, wave = tid >> 6;
    const int quad = lane >> 4, l16 = lane & 15;
    const int wq = wave * 32;

    f32x4 acc[2][4];
    #pragma unroll
    for (int t = 0; t < 2; t++)
        #pragma unroll
        for (int nt = 0; nt < 4; nt++) acc[t][nt] = (f32x4){0.f,0.f,0.f,0.f};

    const int sr = tid >> 3, sc = (tid & 7) * 8;

    for (int k0 = 0; k0 < DM; k0 += 64) {
        __syncthreads();
        #pragma unroll
        for (int i = 0; i < 4; i++) {
            int r = i * 32 + sr;
            *(uint4*)&As[r][sc] = *(const uint4*)(A + (size_t)(m0 + r) * DM + k0 + sc);
        }
        #pragma unroll
        for (int i = 0; i < 2; i++) {
            int r = i * 32 + sr;
            *(uint4*)&Bs[r][sc] = *(const uint4*)(WoT + (size_t)(n0 + r) * DM + k0 + sc);
        }
        __syncthreads();
        #pragma unroll
        for (int ksub = 0; ksub < 2; ksub++) {
            bf16x8 a0 = *(const bf16x8*)&As[wq + l16][ksub * 32 + quad * 8];
            bf16x8 a1 = *(const bf16x8*)&As[wq + 16 + l16][ksub * 32 + quad * 8];
            bf16x8 bf[4];
            #pragma unroll
            for (int nt = 0; nt < 4; nt++)
                bf[nt] = *(const bf16x8*)&Bs[nt * 16 + l16][ksub * 32 + quad * 8];
            #pragma unroll
            for (int nt = 0; nt < 4; nt++) {
                acc[0][nt] = __builtin_amdgcn_mfma_f32_16x16x32_bf16(a0, bf[nt], acc[0][nt], 0, 0, 0);
                acc[1][nt] = __builtin_amdgcn_mfma_f32_16x16x32_bf16(a1, bf[nt], acc[1][nt], 0, 0, 0);
            }
        }
    }

    #pragma unroll
    for (int t = 0; t < 2; t++) {
        #pragma unroll
        for (int nt = 0; nt < 4; nt++) {
            int n = n0 + nt * 16 + l16;
            float bsv = bias[n];
            #pragma unroll
            for (int r = 0; r < 4; r++) {
                int m = m0 + wq + t * 16 + quad * 4 + r;
                Y[(size_t)m * DM + n] = acc[t][nt][r] + bsv;
            }
        }
    }
}

// ---------------------------------------------------------------------------
// MFMA flash attention (pre-split bf16 inputs). One block = (bt*h, 128 Q-rows).
// QK^T split-bf16 3-MFMA; register softmax (shfl over l16); P via wave-private
// LDS; PV plain bf16 MFMA. Qh/Ql/Kh/Kl (bt,h,s,d) bf16; Vt (bt,h,d,s) bf16.
// ---------------------------------------------------------------------------
#define QTILE 128

__global__ __launch_bounds__(256) void attn_mfma_kernel(
    const uint16_t* __restrict__ Qhg, const uint16_t* __restrict__ Qlg,
    const uint16_t* __restrict__ Khg, const uint16_t* __restrict__ Klg,
    const uint16_t* __restrict__ Vtg, const int* __restrict__ modality,
    const int* __restrict__ nlat_p, uint16_t* __restrict__ ctx)
{
    __shared__ uint16_t KhS[64][72];   // K chunk hi [key][d]
    __shared__ uint16_t KlS[64][72];   // K chunk lo
    __shared__ uint16_t Vs[64][72];    // V chunk [d][key]
    __shared__ uint16_t Ps[QTILE][72]; // P [qrow][key], wave-private rows
    __shared__ int modk_s[64];

    const int bh = blockIdx.x;
    const int bt = bh / NHEAD, h = bh % NHEAD;
    const int q0 = blockIdx.y * QTILE;
    const int tid = threadIdx.x, lane = tid & 63, wave = tid >> 6;
    const int quad = lane >> 4, l16 = lane & 15;
    const int wq = wave * 32;

    const size_t hb = (size_t)bh * SEQL * HDIM;
    const int nlat = nlat_p[0];

    // Q fragments: direct bf16 loads (pre-split)
    bf16x8 qh[2][2], ql[2][2];
    #pragma unroll
    for (int t = 0; t < 2; t++)
        #pragma unroll
        for (int ks = 0; ks < 2; ks++) {
            size_t o = hb + (size_t)(q0 + wq + t*16 + l16) * HDIM + ks*32 + quad*8;
            qh[t][ks] = *(const bf16x8*)(Qhg + o);
            ql[t][ks] = *(const bf16x8*)(Qlg + o);
        }

    int  mq[2][4]; bool lat_[2][4];
    #pragma unroll
    for (int t = 0; t < 2; t++)
        #pragma unroll
        for (int r = 0; r < 4; r++) {
            int row = q0 + wq + t*16 + quad*4 + r;
            mq[t][r]   = modality[row];
            lat_[t][r] = row < nlat;
        }

    float mrow[2][4], lrow[2][4];
    #pragma unroll
    for (int t = 0; t < 2; t++)
        #pragma unroll
        for (int r = 0; r < 4; r++) { mrow[t][r] = -3e38f; lrow[t][r] = 0.f; }
    f32x4 O[2][4];
    #pragma unroll
    for (int t = 0; t < 2; t++)
        #pragma unroll
        for (int dt = 0; dt < 4; dt++) O[t][dt] = (f32x4){0.f,0.f,0.f,0.f};

    for (int s0 = 0; s0 < SEQL; s0 += 64) {
        __syncthreads();
        {   // stage K hi/lo + V: contiguous uint4 copies, no conversion
            int rr = tid >> 2, c0 = (tid & 3) * 16;
            const uint16_t* kp = Khg + hb + (size_t)(s0 + rr) * HDIM + c0;
            const uint16_t* lp = Klg + hb + (size_t)(s0 + rr) * HDIM + c0;
            const uint16_t* vp = Vtg + hb + (size_t)rr * SEQL + s0 + c0;  // rr = d
            *(uint4*)&KhS[rr][c0]     = *(const uint4*)kp;
            *(uint4*)&KhS[rr][c0 + 8] = *((const uint4*)kp + 1);
            *(uint4*)&KlS[rr][c0]     = *(const uint4*)lp;
            *(uint4*)&KlS[rr][c0 + 8] = *((const uint4*)lp + 1);
            *(uint4*)&Vs[rr][c0]      = *(const uint4*)vp;
            *(uint4*)&Vs[rr][c0 + 8]  = *((const uint4*)vp + 1);
        }
        if (tid < 64) modk_s[tid] = modality[s0 + tid];
        __syncthreads();

        // scores: split-bf16 3-MFMA
        f32x4 S[2][4];
        #pragma unroll
        for (int t = 0; t < 2; t++)
            #pragma unroll
            for (int n = 0; n < 4; n++) S[t][n] = (f32x4){0.f,0.f,0.f,0.f};
        #pragma unroll
        for (int n = 0; n < 4; n++) {
            #pragma unroll
            for (int ks = 0; ks < 2; ks++) {
                bf16x8 kh = *(const bf16x8*)&KhS[n*16 + l16][ks*32 + quad*8];
                bf16x8 kl = *(const bf16x8*)&KlS[n*16 + l16][ks*32 + quad*8];
                #pragma unroll
                for (int t = 0; t < 2; t++) {
                    S[t][n] = __builtin_amdgcn_mfma_f32_16x16x32_bf16(ql[t][ks], kh, S[t][n], 0, 0, 0);
                    S[t][n] = __builtin_amdgcn_mfma_f32_16x16x32_bf16(qh[t][ks], kl, S[t][n], 0, 0, 0);
                    S[t][n] = __builtin_amdgcn_mfma_f32_16x16x32_bf16(qh[t][ks], kh, S[t][n], 0, 0, 0);
                }
            }
        }

        // mask (C layout: col = n*16+l16, row = quad*4+r)
        int mk[4];
        #pragma unroll
        for (int n = 0; n < 4; n++) mk[n] = modk_s[n*16 + l16];
        #pragma unroll
        for (int t = 0; t < 2; t++)
            #pragma unroll
            for (int n = 0; n < 4; n++)
                #pragma unroll
                for (int r = 0; r < 4; r++)
                    if (!(lat_[t][r] || (mq[t][r] == mk[n]))) S[t][n][r] = -3e38f;

        // online softmax (shuffle over l16)
        #pragma unroll
        for (int t = 0; t < 2; t++) {
            #pragma unroll
            for (int r = 0; r < 4; r++) {
                float mc = fmaxf(fmaxf(S[t][0][r], S[t][1][r]),
                                 fmaxf(S[t][2][r], S[t][3][r]));
                #pragma unroll
                for (int off = 1; off <= 8; off <<= 1)
                    mc = fmaxf(mc, __shfl_xor(mc, off, 64));
                float mo = mrow[t][r];
                float mn = fmaxf(mo, mc);
                float al = __expf(mo - mn);
                float g  = (mn <= -1e37f) ? 0.f : 1.f;
                float sum = 0.f;
                #pragma unroll
                for (int n = 0; n < 4; n++) {
                    float p = __expf(S[t][n][r] - mn) * g;
                    Ps[wq + t*16 + quad*4 + r][n*16 + l16] = f2b(p);
                    sum += p;
                }
                #pragma unroll
                for (int off = 1; off <= 8; off <<= 1)
                    sum += __shfl_xor(sum, off, 64);
                lrow[t][r] = lrow[t][r] * al + sum;
                mrow[t][r] = mn;
                #pragma unroll
                for (int dt = 0; dt < 4; dt++) O[t][dt][r] *= al;
            }
        }

        // PV
        #pragma unroll
        for (int ks = 0; ks < 2; ks++) {
            bf16x8 pa[2];
            #pragma unroll
            for (int t = 0; t < 2; t++)
                pa[t] = *(const bf16x8*)&Ps[wq + t*16 + l16][ks*32 + quad*8];
            #pragma unroll
            for (int dt = 0; dt < 4; dt++) {
                bf16x8 vb = *(const bf16x8*)&Vs[dt*16 + l16][ks*32 + quad*8];
                #pragma unroll
                for (int t = 0; t < 2; t++)
                    O[t][dt] = __builtin_amdgcn_mfma_f32_16x16x32_bf16(pa[t], vb, O[t][dt], 0, 0, 0);
            }
        }
    }

    // epilogue: ctx = O / l
    #pragma unroll
    for (int t = 0; t < 2; t++) {
        float inv[4];
        #pragma unroll
        for (int r = 0; r < 4; r++) inv[r] = 1.0f / fmaxf(lrow[t][r], 1e-30f);
        #pragma unroll
        for (int dt = 0; dt < 4; dt++) {
            #pragma unroll
            for (int r = 0; r < 4; r++) {
                int row = q0 + wq + t*16 + quad*4 + r;
                ctx[(size_t)(bt * SEQL + row) * DM + h*HDIM + dt*16 + l16] =
                    f2b(O[t][dt][r] * inv[r]);
            }
        }
    }
}

// ---------------------------------------------------------------------------
extern "C" void kernel_launch(void* const* d_in, const int* in_sizes, int n_in,
                              void* d_out, int out_size, void* d_ws, size_t ws_size,
                              hipStream_t stream) {
    const float* X  = (const float*)d_in[0];
    const float* Wq = (const float*)d_in[1];
    const float* bq = (const float*)d_in[2];
    const float* Wk = (const float*)d_in[3];
    const float* bk = (const float*)d_in[4];
    const float* Wv = (const float*)d_in[5];
    const float* bv = (const float*)d_in[6];
    const float* Wo = (const float*)d_in[7];
    const float* bo = (const float*)d_in[8];
    const int* modality = (const int*)d_in[9];
    const int* nlat     = (const int*)d_in[10];

    const size_t per = (size_t)MTOT * DM;   // 12.6M elements
    const size_t wsz = (size_t)DM * DM;     // 589k elements
    uint16_t* p = (uint16_t*)d_ws;
    uint16_t* Xh   = p; p += per;
    uint16_t* Xl   = p; p += per;
    uint16_t* WqTh = p; p += wsz;
    uint16_t* WqTl = p; p += wsz;
    uint16_t* WkTh = p; p += wsz;
    uint16_t* WkTl = p; p += wsz;
    uint16_t* WvT  = p; p += wsz;
    uint16_t* WoT  = p; p += wsz;
    uint16_t* Qh   = p; p += per;
    uint16_t* Ql   = p; p += per;
    uint16_t* Kh   = p; p += per;
    uint16_t* Kl   = p; p += per;
    uint16_t* Vt   = p; p += per;
    uint16_t* c_ws = Xh;   // alias: Xh dead after qkv_gemm_v2; ctx written by attn

    split_x_kernel<<<dim3(per / 1024), 256, 0, stream>>>(X, Xh, Xl);
    wprep_kernel<<<dim3(DM / 32, DM / 32, 4), 256, 0, stream>>>(
        Wq, Wk, Wv, Wo, WqTh, WqTl, WkTh, WkTl, WvT, WoT);
    qkv_gemm_v2<<<dim3(MTOT / 128, DM / 64, 3), 256, 0, stream>>>(
        Xh, Xl, WqTh, WqTl, WkTh, WkTl, WvT, bq, bk, bv, Qh, Ql, Kh, Kl, Vt);
    attn_mfma_kernel<<<dim3(BT_N * NHEAD, SEQL / QTILE), 256, 0, stream>>>(
        Qh, Ql, Kh, Kl, Vt, modality, nlat, c_ws);
    out_proj_v2<<<dim3(MTOT / 128, DM / 64), 256, 0, stream>>>(
        c_ws, WoT, bo, (float*)d_out);
}

// Round 7
// 474.344 us; speedup vs baseline: 6.1818x; 1.1042x over previous
//
#include <hip/hip_runtime.h>
#include <hip/hip_bf16.h>
#include <stdint.h>

// Problem constants
#define BT_N  32      // B*T
#define SEQL  512     // S
#define DM    768     // D_MODEL
#define NHEAD 12
#define HDIM  64
#define MTOT  (BT_N * SEQL)   // 16384 rows

typedef __bf16 bf16x8 __attribute__((ext_vector_type(8)));
typedef float  f32x4  __attribute__((ext_vector_type(4)));

__device__ __forceinline__ float b2f(uint16_t u)  { return __uint_as_float(((uint32_t)u) << 16); }
__device__ __forceinline__ uint16_t f2b(float f) {
    uint32_t u = __float_as_uint(f);
    return (uint16_t)((u + 0x7fffu + ((u >> 16) & 1u)) >> 16);  // RNE
}
__device__ __forceinline__ void split_bf16(float x, uint16_t& hi, uint16_t& lo) {
    hi = f2b(x);
    lo = f2b(x - b2f(hi));
}

// ---------------------------------------------------------------------------
// Prepass 1: X fp32 -> Xh, Xl bf16 (hi/lo split). 4 elems/thread.
// ---------------------------------------------------------------------------
__global__ __launch_bounds__(256) void split_x_kernel(
    const float* __restrict__ X, uint16_t* __restrict__ Xh, uint16_t* __restrict__ Xl)
{
    size_t i = ((size_t)blockIdx.x * 256 + threadIdx.x) * 4;
    float4 v = *(const float4*)(X + i);
    float xx[4] = {v.x, v.y, v.z, v.w};
    ushort4 h, l;
    uint16_t hh, ll;
    split_bf16(xx[0], hh, ll); h.x = hh; l.x = ll;
    split_bf16(xx[1], hh, ll); h.y = hh; l.y = ll;
    split_bf16(xx[2], hh, ll); h.z = hh; l.z = ll;
    split_bf16(xx[3], hh, ll); h.w = hh; l.w = ll;
    *(ushort4*)(Xh + i) = h;
    *(ushort4*)(Xl + i) = l;
}

// ---------------------------------------------------------------------------
// Prepass 2: weight transpose (+split for Wq,Wk). W row-major (k,n) fp32 ->
// WT [n][k] bf16 (hi, and lo for z<2). 32x32 LDS tile transpose.
// z: 0=Wq(split), 1=Wk(split), 2=Wv(plain), 3=Wo(plain)
// ---------------------------------------------------------------------------
__global__ __launch_bounds__(256) void wprep_kernel(
    const float* __restrict__ Wq, const float* __restrict__ Wk,
    const float* __restrict__ Wv, const float* __restrict__ Wo,
    uint16_t* __restrict__ WqTh, uint16_t* __restrict__ WqTl,
    uint16_t* __restrict__ WkTh, uint16_t* __restrict__ WkTl,
    uint16_t* __restrict__ WvT,  uint16_t* __restrict__ WoT)
{
    __shared__ float tile[32][33];
    const int z = blockIdx.z;
    const float* W; uint16_t* Th; uint16_t* Tl;
    if (z == 0)      { W = Wq; Th = WqTh; Tl = WqTl; }
    else if (z == 1) { W = Wk; Th = WkTh; Tl = WkTl; }
    else if (z == 2) { W = Wv; Th = WvT;  Tl = nullptr; }
    else             { W = Wo; Th = WoT;  Tl = nullptr; }

    const int k0 = blockIdx.x * 32, n0 = blockIdx.y * 32;
    const int tid = threadIdx.x;
    {
        int r = tid >> 3, c = (tid & 7) * 4;
        *(float4*)&tile[r][c] = *(const float4*)(W + (size_t)(k0 + r) * DM + n0 + c);
    }
    __syncthreads();
    {
        int nl = tid >> 3, kk = (tid & 7) * 4;
        ushort4 h, l;
        uint16_t hh, ll;
        float v0 = tile[kk + 0][nl], v1 = tile[kk + 1][nl];
        float v2 = tile[kk + 2][nl], v3 = tile[kk + 3][nl];
        split_bf16(v0, hh, ll); h.x = hh; l.x = ll;
        split_bf16(v1, hh, ll); h.y = hh; l.y = ll;
        split_bf16(v2, hh, ll); h.z = hh; l.z = ll;
        split_bf16(v3, hh, ll); h.w = hh; l.w = ll;
        size_t o = (size_t)(n0 + nl) * DM + k0 + kk;
        *(ushort4*)(Th + o) = h;
        if (Tl) *(ushort4*)(Tl + o) = l;
    }
}

// ---------------------------------------------------------------------------
// QKV GEMM v3: FUSED split-bf16 passes in a single k-loop.
// Block: 256 thr, tile 128(m) x 64(n), BK=64. Wave: 2 m-tiles x 4 n-tiles.
// z<2: stage Ah/Al/Bh/Bl once per k-step, 3 MFMA per fragment pair
//      (48 MFMA : 24 ds_read : 2 barriers per k-step).
// z=2: plain 1-MFMA (V), hi tiles only.
// ---------------------------------------------------------------------------
__global__ __launch_bounds__(256) void qkv_gemm_v3(
    const uint16_t* __restrict__ Xh, const uint16_t* __restrict__ Xl,
    const uint16_t* __restrict__ WqTh, const uint16_t* __restrict__ WqTl,
    const uint16_t* __restrict__ WkTh, const uint16_t* __restrict__ WkTl,
    const uint16_t* __restrict__ WvT,
    const float* __restrict__ bq, const float* __restrict__ bk, const float* __restrict__ bv,
    uint16_t* __restrict__ Qh, uint16_t* __restrict__ Ql,
    uint16_t* __restrict__ Kh, uint16_t* __restrict__ Kl,
    uint16_t* __restrict__ Vt)
{
    __shared__ uint16_t AhS[128][72], AlS[128][72];   // [m][k], stride 144 B
    __shared__ uint16_t BhS[64][72],  BlS[64][72];    // [n][k]

    const int m0 = blockIdx.x * 128;
    const int n0 = blockIdx.y * 64;
    const int z  = blockIdx.z;

    const uint16_t* Bh_g; const uint16_t* Bl_g = nullptr; const float* bias;
    if (z == 0)      { Bh_g = WqTh; Bl_g = WqTl; bias = bq; }
    else if (z == 1) { Bh_g = WkTh; Bl_g = WkTl; bias = bk; }
    else             { Bh_g = WvT;               bias = bv; }

    const int tid  = threadIdx.x;
    const int lane = tid & 63, wave = tid >> 6;
    const int quad = lane >> 4, l16 = lane & 15;
    const int wq = wave * 32;

    f32x4 acc[2][4];
    #pragma unroll
    for (int t = 0; t < 2; t++)
        #pragma unroll
        for (int nt = 0; nt < 4; nt++) acc[t][nt] = (f32x4){0.f,0.f,0.f,0.f};

    const int sr = tid >> 3, sc = (tid & 7) * 8;   // staging: 16B contiguous per thread

    for (int k0 = 0; k0 < DM; k0 += 64) {
        __syncthreads();
        #pragma unroll
        for (int i = 0; i < 4; i++) {   // A hi tile 128x64
            int r = i * 32 + sr;
            *(uint4*)&AhS[r][sc] = *(const uint4*)(Xh + (size_t)(m0 + r) * DM + k0 + sc);
        }
        #pragma unroll
        for (int i = 0; i < 2; i++) {   // B hi tile 64x64
            int r = i * 32 + sr;
            *(uint4*)&BhS[r][sc] = *(const uint4*)(Bh_g + (size_t)(n0 + r) * DM + k0 + sc);
        }
        if (z < 2) {
            #pragma unroll
            for (int i = 0; i < 4; i++) {   // A lo tile
                int r = i * 32 + sr;
                *(uint4*)&AlS[r][sc] = *(const uint4*)(Xl + (size_t)(m0 + r) * DM + k0 + sc);
            }
            #pragma unroll
            for (int i = 0; i < 2; i++) {   // B lo tile
                int r = i * 32 + sr;
                *(uint4*)&BlS[r][sc] = *(const uint4*)(Bl_g + (size_t)(n0 + r) * DM + k0 + sc);
            }
        }
        __syncthreads();
        #pragma unroll
        for (int ksub = 0; ksub < 2; ksub++) {
            bf16x8 ah[2], bh[4];
            ah[0] = *(const bf16x8*)&AhS[wq + l16][ksub * 32 + quad * 8];
            ah[1] = *(const bf16x8*)&AhS[wq + 16 + l16][ksub * 32 + quad * 8];
            #pragma unroll
            for (int nt = 0; nt < 4; nt++)
                bh[nt] = *(const bf16x8*)&BhS[nt * 16 + l16][ksub * 32 + quad * 8];
            if (z < 2) {
                bf16x8 al[2], bl[4];
                al[0] = *(const bf16x8*)&AlS[wq + l16][ksub * 32 + quad * 8];
                al[1] = *(const bf16x8*)&AlS[wq + 16 + l16][ksub * 32 + quad * 8];
                #pragma unroll
                for (int nt = 0; nt < 4; nt++)
                    bl[nt] = *(const bf16x8*)&BlS[nt * 16 + l16][ksub * 32 + quad * 8];
                #pragma unroll
                for (int t = 0; t < 2; t++)
                    #pragma unroll
                    for (int nt = 0; nt < 4; nt++) {
                        acc[t][nt] = __builtin_amdgcn_mfma_f32_16x16x32_bf16(al[t], bh[nt], acc[t][nt], 0, 0, 0);
                        acc[t][nt] = __builtin_amdgcn_mfma_f32_16x16x32_bf16(ah[t], bl[nt], acc[t][nt], 0, 0, 0);
                        acc[t][nt] = __builtin_amdgcn_mfma_f32_16x16x32_bf16(ah[t], bh[nt], acc[t][nt], 0, 0, 0);
                    }
            } else {
                #pragma unroll
                for (int t = 0; t < 2; t++)
                    #pragma unroll
                    for (int nt = 0; nt < 4; nt++)
                        acc[t][nt] = __builtin_amdgcn_mfma_f32_16x16x32_bf16(ah[t], bh[nt], acc[t][nt], 0, 0, 0);
            }
        }
    }

    // epilogue
    const float scale = (z == 0) ? 0.125f : 1.0f;
    uint16_t* OutH = (z == 0) ? Qh : Kh;
    uint16_t* OutL = (z == 0) ? Ql : Kl;
    #pragma unroll
    for (int t = 0; t < 2; t++) {
        #pragma unroll
        for (int nt = 0; nt < 4; nt++) {
            int n = n0 + nt * 16 + l16;
            float bsv = bias[n];
            int hh = n >> 6, d = n & 63;
            int mbase = m0 + wq + t * 16 + quad * 4;   // C/D: row = quad*4 + r
            if (z == 2) {
                int bt = mbase >> 9, sb = mbase & 511;
                ushort4 pk;
                pk.x = f2b(acc[t][nt][0] + bsv);
                pk.y = f2b(acc[t][nt][1] + bsv);
                pk.z = f2b(acc[t][nt][2] + bsv);
                pk.w = f2b(acc[t][nt][3] + bsv);
                *(ushort4*)&Vt[(((size_t)bt * NHEAD + hh) * HDIM + d) * SEQL + sb] = pk;
            } else {
                #pragma unroll
                for (int r = 0; r < 4; r++) {
                    int m = mbase + r;
                    float val = (acc[t][nt][r] + bsv) * scale;
                    uint16_t vh, vl; split_bf16(val, vh, vl);
                    int bt = m >> 9, s = m & 511;
                    size_t idx = (((size_t)bt * NHEAD + hh) * SEQL + s) * HDIM + d;
                    OutH[idx] = vh; OutL[idx] = vl;
                }
            }
        }
    }
}

// ---------------------------------------------------------------------------
// Output projection v2: Y = ctx @ Wo + bo. ctx bf16 row-major, WoT [n][k] bf16.
// 128x64 tile, 1 pass. Y fp32 to d_out.
// ---------------------------------------------------------------------------
__global__ __launch_bounds__(256) void out_proj_v2(
    const uint16_t* __restrict__ A, const uint16_t* __restrict__ WoT,
    const float* __restrict__ bias, float* __restrict__ Y)
{
    __shared__ uint16_t As[128][72];
    __shared__ uint16_t Bs[64][72];

    const int m0 = blockIdx.x * 128;
    const int n0 = blockIdx.y * 64;
    const int tid  = threadIdx.x;
    const int lane = tid & 63, wave = tid >> 6;
    const int quad = lane >> 4, l16 = lane & 15;
    const int wq = wave * 32;

    f32x4 acc[2][4];
    #pragma unroll
    for (int t = 0; t < 2; t++)
        #pragma unroll
        for (int nt = 0; nt < 4; nt++) acc[t][nt] = (f32x4){0.f,0.f,0.f,0.f};

    const int sr = tid >> 3, sc = (tid & 7) * 8;

    for (int k0 = 0; k0 < DM; k0 += 64) {
        __syncthreads();
        #pragma unroll
        for (int i = 0; i < 4; i++) {
            int r = i * 32 + sr;
            *(uint4*)&As[r][sc] = *(const uint4*)(A + (size_t)(m0 + r) * DM + k0 + sc);
        }
        #pragma unroll
        for (int i = 0; i < 2; i++) {
            int r = i * 32 + sr;
            *(uint4*)&Bs[r][sc] = *(const uint4*)(WoT + (size_t)(n0 + r) * DM + k0 + sc);
        }
        __syncthreads();
        #pragma unroll
        for (int ksub = 0; ksub < 2; ksub++) {
            bf16x8 a0 = *(const bf16x8*)&As[wq + l16][ksub * 32 + quad * 8];
            bf16x8 a1 = *(const bf16x8*)&As[wq + 16 + l16][ksub * 32 + quad * 8];
            bf16x8 bf[4];
            #pragma unroll
            for (int nt = 0; nt < 4; nt++)
                bf[nt] = *(const bf16x8*)&Bs[nt * 16 + l16][ksub * 32 + quad * 8];
            #pragma unroll
            for (int nt = 0; nt < 4; nt++) {
                acc[0][nt] = __builtin_amdgcn_mfma_f32_16x16x32_bf16(a0, bf[nt], acc[0][nt], 0, 0, 0);
                acc[1][nt] = __builtin_amdgcn_mfma_f32_16x16x32_bf16(a1, bf[nt], acc[1][nt], 0, 0, 0);
            }
        }
    }

    #pragma unroll
    for (int t = 0; t < 2; t++) {
        #pragma unroll
        for (int nt = 0; nt < 4; nt++) {
            int n = n0 + nt * 16 + l16;
            float bsv = bias[n];
            #pragma unroll
            for (int r = 0; r < 4; r++) {
                int m = m0 + wq + t * 16 + quad * 4 + r;
                Y[(size_t)m * DM + n] = acc[t][nt][r] + bsv;
            }
        }
    }
}

// ---------------------------------------------------------------------------
// MFMA flash attention (pre-split bf16 inputs). One block = (bt*h, 128 Q-rows).
// QK^T split-bf16 3-MFMA; register softmax (shfl over l16); P via wave-private
// LDS; PV plain bf16 MFMA. Qh/Ql/Kh/Kl (bt,h,s,d) bf16; Vt (bt,h,d,s) bf16.
// ---------------------------------------------------------------------------
#define QTILE 128

__global__ __launch_bounds__(256) void attn_mfma_kernel(
    const uint16_t* __restrict__ Qhg, const uint16_t* __restrict__ Qlg,
    const uint16_t* __restrict__ Khg, const uint16_t* __restrict__ Klg,
    const uint16_t* __restrict__ Vtg, const int* __restrict__ modality,
    const int* __restrict__ nlat_p, uint16_t* __restrict__ ctx)
{
    __shared__ uint16_t KhS[64][72];   // K chunk hi [key][d]
    __shared__ uint16_t KlS[64][72];   // K chunk lo
    __shared__ uint16_t Vs[64][72];    // V chunk [d][key]
    __shared__ uint16_t Ps[QTILE][72]; // P [qrow][key], wave-private rows
    __shared__ int modk_s[64];

    const int bh = blockIdx.x;
    const int bt = bh / NHEAD, h = bh % NHEAD;
    const int q0 = blockIdx.y * QTILE;
    const int tid = threadIdx.x, lane = tid & 63, wave = tid >> 6;
    const int quad = lane >> 4, l16 = lane & 15;
    const int wq = wave * 32;

    const size_t hb = (size_t)bh * SEQL * HDIM;
    const int nlat = nlat_p[0];

    bf16x8 qh[2][2], ql[2][2];
    #pragma unroll
    for (int t = 0; t < 2; t++)
        #pragma unroll
        for (int ks = 0; ks < 2; ks++) {
            size_t o = hb + (size_t)(q0 + wq + t*16 + l16) * HDIM + ks*32 + quad*8;
            qh[t][ks] = *(const bf16x8*)(Qhg + o);
            ql[t][ks] = *(const bf16x8*)(Qlg + o);
        }

    int  mq[2][4]; bool lat_[2][4];
    #pragma unroll
    for (int t = 0; t < 2; t++)
        #pragma unroll
        for (int r = 0; r < 4; r++) {
            int row = q0 + wq + t*16 + quad*4 + r;
            mq[t][r]   = modality[row];
            lat_[t][r] = row < nlat;
        }

    float mrow[2][4], lrow[2][4];
    #pragma unroll
    for (int t = 0; t < 2; t++)
        #pragma unroll
        for (int r = 0; r < 4; r++) { mrow[t][r] = -3e38f; lrow[t][r] = 0.f; }
    f32x4 O[2][4];
    #pragma unroll
    for (int t = 0; t < 2; t++)
        #pragma unroll
        for (int dt = 0; dt < 4; dt++) O[t][dt] = (f32x4){0.f,0.f,0.f,0.f};

    for (int s0 = 0; s0 < SEQL; s0 += 64) {
        __syncthreads();
        {   // stage K hi/lo + V: contiguous uint4 copies
            int rr = tid >> 2, c0 = (tid & 3) * 16;
            const uint16_t* kp = Khg + hb + (size_t)(s0 + rr) * HDIM + c0;
            const uint16_t* lp = Klg + hb + (size_t)(s0 + rr) * HDIM + c0;
            const uint16_t* vp = Vtg + hb + (size_t)rr * SEQL + s0 + c0;  // rr = d
            *(uint4*)&KhS[rr][c0]     = *(const uint4*)kp;
            *(uint4*)&KhS[rr][c0 + 8] = *((const uint4*)kp + 1);
            *(uint4*)&KlS[rr][c0]     = *(const uint4*)lp;
            *(uint4*)&KlS[rr][c0 + 8] = *((const uint4*)lp + 1);
            *(uint4*)&Vs[rr][c0]      = *(const uint4*)vp;
            *(uint4*)&Vs[rr][c0 + 8]  = *((const uint4*)vp + 1);
        }
        if (tid < 64) modk_s[tid] = modality[s0 + tid];
        __syncthreads();

        f32x4 S[2][4];
        #pragma unroll
        for (int t = 0; t < 2; t++)
            #pragma unroll
            for (int n = 0; n < 4; n++) S[t][n] = (f32x4){0.f,0.f,0.f,0.f};
        #pragma unroll
        for (int n = 0; n < 4; n++) {
            #pragma unroll
            for (int ks = 0; ks < 2; ks++) {
                bf16x8 kh = *(const bf16x8*)&KhS[n*16 + l16][ks*32 + quad*8];
                bf16x8 kl = *(const bf16x8*)&KlS[n*16 + l16][ks*32 + quad*8];
                #pragma unroll
                for (int t = 0; t < 2; t++) {
                    S[t][n] = __builtin_amdgcn_mfma_f32_16x16x32_bf16(ql[t][ks], kh, S[t][n], 0, 0, 0);
                    S[t][n] = __builtin_amdgcn_mfma_f32_16x16x32_bf16(qh[t][ks], kl, S[t][n], 0, 0, 0);
                    S[t][n] = __builtin_amdgcn_mfma_f32_16x16x32_bf16(qh[t][ks], kh, S[t][n], 0, 0, 0);
                }
            }
        }

        int mk[4];
        #pragma unroll
        for (int n = 0; n < 4; n++) mk[n] = modk_s[n*16 + l16];
        #pragma unroll
        for (int t = 0; t < 2; t++)
            #pragma unroll
            for (int n = 0; n < 4; n++)
                #pragma unroll
                for (int r = 0; r < 4; r++)
                    if (!(lat_[t][r] || (mq[t][r] == mk[n]))) S[t][n][r] = -3e38f;

        #pragma unroll
        for (int t = 0; t < 2; t++) {
            #pragma unroll
            for (int r = 0; r < 4; r++) {
                float mc = fmaxf(fmaxf(S[t][0][r], S[t][1][r]),
                                 fmaxf(S[t][2][r], S[t][3][r]));
                #pragma unroll
                for (int off = 1; off <= 8; off <<= 1)
                    mc = fmaxf(mc, __shfl_xor(mc, off, 64));
                float mo = mrow[t][r];
                float mn = fmaxf(mo, mc);
                float al = __expf(mo - mn);
                float g  = (mn <= -1e37f) ? 0.f : 1.f;
                float sum = 0.f;
                #pragma unroll
                for (int n = 0; n < 4; n++) {
                    float p = __expf(S[t][n][r] - mn) * g;
                    Ps[wq + t*16 + quad*4 + r][n*16 + l16] = f2b(p);
                    sum += p;
                }
                #pragma unroll
                for (int off = 1; off <= 8; off <<= 1)
                    sum += __shfl_xor(sum, off, 64);
                lrow[t][r] = lrow[t][r] * al + sum;
                mrow[t][r] = mn;
                #pragma unroll
                for (int dt = 0; dt < 4; dt++) O[t][dt][r] *= al;
            }
        }

        #pragma unroll
        for (int ks = 0; ks < 2; ks++) {
            bf16x8 pa[2];
            #pragma unroll
            for (int t = 0; t < 2; t++)
                pa[t] = *(const bf16x8*)&Ps[wq + t*16 + l16][ks*32 + quad*8];
            #pragma unroll
            for (int dt = 0; dt < 4; dt++) {
                bf16x8 vb = *(const bf16x8*)&Vs[dt*16 + l16][ks*32 + quad*8];
                #pragma unroll
                for (int t = 0; t < 2; t++)
                    O[t][dt] = __builtin_amdgcn_mfma_f32_16x16x32_bf16(pa[t], vb, O[t][dt], 0, 0, 0);
            }
        }
    }

    #pragma unroll
    for (int t = 0; t < 2; t++) {
        float inv[4];
        #pragma unroll
        for (int r = 0; r < 4; r++) inv[r] = 1.0f / fmaxf(lrow[t][r], 1e-30f);
        #pragma unroll
        for (int dt = 0; dt < 4; dt++) {
            #pragma unroll
            for (int r = 0; r < 4; r++) {
                int row = q0 + wq + t*16 + quad*4 + r;
                ctx[(size_t)(bt * SEQL + row) * DM + h*HDIM + dt*16 + l16] =
                    f2b(O[t][dt][r] * inv[r]);
            }
        }
    }
}

// ---------------------------------------------------------------------------
extern "C" void kernel_launch(void* const* d_in, const int* in_sizes, int n_in,
                              void* d_out, int out_size, void* d_ws, size_t ws_size,
                              hipStream_t stream) {
    const float* X  = (const float*)d_in[0];
    const float* Wq = (const float*)d_in[1];
    const float* bq = (const float*)d_in[2];
    const float* Wk = (const float*)d_in[3];
    const float* bk = (const float*)d_in[4];
    const float* Wv = (const float*)d_in[5];
    const float* bv = (const float*)d_in[6];
    const float* Wo = (const float*)d_in[7];
    const float* bo = (const float*)d_in[8];
    const int* modality = (const int*)d_in[9];
    const int* nlat     = (const int*)d_in[10];

    const size_t per = (size_t)MTOT * DM;   // 12.6M elements
    const size_t wsz = (size_t)DM * DM;     // 589k elements
    uint16_t* p = (uint16_t*)d_ws;
    uint16_t* Xh   = p; p += per;
    uint16_t* Xl   = p; p += per;
    uint16_t* WqTh = p; p += wsz;
    uint16_t* WqTl = p; p += wsz;
    uint16_t* WkTh = p; p += wsz;
    uint16_t* WkTl = p; p += wsz;
    uint16_t* WvT  = p; p += wsz;
    uint16_t* WoT  = p; p += wsz;
    uint16_t* Qh   = p; p += per;
    uint16_t* Ql   = p; p += per;
    uint16_t* Kh   = p; p += per;
    uint16_t* Kl   = p; p += per;
    uint16_t* Vt   = p; p += per;
    uint16_t* c_ws = Xh;   // alias: Xh dead after qkv_gemm_v3

    split_x_kernel<<<dim3(per / 1024), 256, 0, stream>>>(X, Xh, Xl);
    wprep_kernel<<<dim3(DM / 32, DM / 32, 4), 256, 0, stream>>>(
        Wq, Wk, Wv, Wo, WqTh, WqTl, WkTh, WkTl, WvT, WoT);
    qkv_gemm_v3<<<dim3(MTOT / 128, DM / 64, 3), 256, 0, stream>>>(
        Xh, Xl, WqTh, WqTl, WkTh, WkTl, WvT, bq, bk, bv, Qh, Ql, Kh, Kl, Vt);
    attn_mfma_kernel<<<dim3(BT_N * NHEAD, SEQL / QTILE), 256, 0, stream>>>(
        Qh, Ql, Kh, Kl, Vt, modality, nlat, c_ws);
    out_proj_v2<<<dim3(MTOT / 128, DM / 64), 256, 0, stream>>>(
        c_ws, WoT, bo, (float*)d_out);
}